// Round 13
// baseline (432.501 us; speedup 1.0000x reference)
//
#include <hip/hip_runtime.h>

#define NN 50000
#define NE 800000
#define NG 128
#define DIM 128
#define CO 10
#define CAP 64     // ELL row capacity; Poisson(16) tail beyond 64 is ~1e-20
#define NPB 2048   // pool blocks
#define GEMB 782   // (NN+63)/64 gemm tile-blocks

typedef unsigned short ushort;
typedef unsigned int uint;
typedef __attribute__((ext_vector_type(8))) short short8;   // 8 bf16
typedef __attribute__((ext_vector_type(4))) float floatx4;

static __device__ __forceinline__ ushort f2bf(float f) {
    uint u = __float_as_uint(f);
    uint r = (u + 0x7FFF + ((u >> 16) & 1)) >> 16;   // RNE
    return (ushort)r;
}
#define EWS (1.0f / 65535.0f)

// ---- prep: wt = bf16(W^T) x2, cnt = 0, sums = 0, done = 0 (one launch) ----
__global__ void k_prep(const float* __restrict__ W1, const float* __restrict__ W2,
                       ushort* __restrict__ wt1, ushort* __restrict__ wt2,
                       int* __restrict__ cnt, float* __restrict__ sums,
                       int* __restrict__ done) {
    int i = blockIdx.x * 256 + threadIdx.x;
    if (i < 16384) {
        wt1[(i & 127) * 128 + (i >> 7)] = f2bf(W1[i]);
    } else if (i < 32768) {
        int j = i - 16384;
        wt2[(j & 127) * 128 + (j >> 7)] = f2bf(W2[j]);
    } else if (i < 32768 + NN) {
        cnt[i - 32768] = 0;
    } else if (i < 32768 + NN + NG * CO + NG) {
        sums[i - 32768 - NN] = 0.0f;
    } else if (i == 32768 + NN + NG * CO + NG) {
        *done = 0;
    }
}

// ---- ELL build: 4B record (ew_u16 << 16 | src_u16) ----
__global__ void k_ell(const int* __restrict__ src, const int* __restrict__ dst,
                      const float* __restrict__ ew, int* __restrict__ cnt,
                      uint* __restrict__ ell) {
    int e = blockIdx.x * blockDim.x + threadIdx.x;
    if (e >= NE) return;
    int d = dst[e], s = src[e];
    int slot = atomicAdd(&cnt[d], 1);
    if (slot < CAP) {
        uint w16 = (uint)__float2uint_rn(ew[e] * 65535.0f);
        ell[(size_t)d * CAP + slot] = (w16 << 16) | (uint)s;
    }
}

// ---- one wave-tile of the MFMA GEMM (16 rows x 128 cols) ----
// dglob: global dinv[row] scale; dlds: wave-local scale[0..15]; either or neither.
static __device__ __forceinline__ void gemm_tile(const void* Ain, int abf,
                                                 const ushort* Wt,
                                                 const float* dglob, const float* dlds,
                                                 ushort* C, int M, int r0, int lane) {
    int quad = lane >> 4;
    int mcol = lane & 15;
    int arow = r0 + mcol;
    if (arow >= M) arow = M - 1;
    floatx4 acc[8];
#pragma unroll
    for (int t = 0; t < 8; t++) acc[t] = (floatx4){0.0f, 0.0f, 0.0f, 0.0f};
    const ushort* Ab = (const ushort*)Ain;
    const float*  Af = (const float*)Ain;
#pragma unroll
    for (int kk = 0; kk < 4; kk++) {
        int koff = kk * 32 + quad * 8;
        short8 a;
        if (abf) {
            a = *(const short8*)&Ab[(size_t)arow * 128 + koff];
        } else {
            const float* ap = &Af[(size_t)arow * 128 + koff];
            float4 x0 = *(const float4*)ap;
            float4 x1 = *(const float4*)(ap + 4);
            union { short8 v; ushort u[8]; } ua;
            ua.u[0] = f2bf(x0.x); ua.u[1] = f2bf(x0.y); ua.u[2] = f2bf(x0.z); ua.u[3] = f2bf(x0.w);
            ua.u[4] = f2bf(x1.x); ua.u[5] = f2bf(x1.y); ua.u[6] = f2bf(x1.z); ua.u[7] = f2bf(x1.w);
            a = ua.v;
        }
#pragma unroll
        for (int t = 0; t < 8; t++) {
            short8 b = *(const short8*)&Wt[(size_t)(t * 16 + mcol) * 128 + koff];
            acc[t] = __builtin_amdgcn_mfma_f32_16x16x32_bf16(a, b, acc[t], 0, 0, 0);
        }
    }
#pragma unroll
    for (int reg = 0; reg < 4; reg++) {
        int row = r0 + quad * 4 + reg;
        if (row < M) {
            float di = dglob ? dglob[row] : (dlds ? dlds[quad * 4 + reg] : 1.0f);
            ushort* cp = &C[(size_t)row * 128];
#pragma unroll
            for (int t = 0; t < 8; t++) cp[t * 16 + mcol] = f2bf(di * acc[t][reg]);
        }
    }
}

// ---- gemm1 + deg: each wave computes dinv for its 16 rows (writes global),
//      then h' = bf16(dinv ⊙ (X @ W1)) ----
__global__ __launch_bounds__(256) void k_gemm1(const float* __restrict__ x,
                                               const ushort* __restrict__ wt1,
                                               const int* __restrict__ cnt,
                                               const uint* __restrict__ ell,
                                               float* __restrict__ dinv,
                                               ushort* __restrict__ hb) {
    __shared__ float sdinv[4][16];
    int wv = threadIdx.x >> 6;
    int lane = threadIdx.x & 63;
    int r0 = blockIdx.x * 64 + wv * 16;
#pragma unroll 4
    for (int r = 0; r < 16; r++) {
        int row = r0 + r;
        if (row < NN) {
            int n = cnt[row];
            float w = (lane < n) ? (float)(ell[(size_t)row * CAP + lane] >> 16) * EWS : 0.0f;
#pragma unroll
            for (int off = 32; off; off >>= 1) w += __shfl_down(w, off);
            if (lane == 0) {
                float dv = rsqrtf(1.0f + w);
                dinv[row] = dv;
                sdinv[wv][r] = dv;
            }
        }
    }
    gemm_tile(x, 0, wt1, nullptr, &sdinv[wv][0], hb, NN, r0, lane);
}

// ---- gemm2: C = bf16(dinv ⊙ (A(bf16) @ W2)) ----
__global__ __launch_bounds__(256) void k_gemm2(const ushort* __restrict__ A,
                                               const ushort* __restrict__ wt2,
                                               const float* __restrict__ dinv,
                                               ushort* __restrict__ C) {
    int wv = threadIdx.x >> 6;
    int lane = threadIdx.x & 63;
    gemm_tile(A, 1, wt2, dinv, nullptr, C, NN, blockIdx.x * 64 + wv * 16, lane);
}

// ---- gather layer 1: gb = bf16(relu(dinv_d*(sum ew*h'[s] + h'[d]) + b1)) ----
__global__ __launch_bounds__(256) void k_gather1(const int* __restrict__ cnt,
                                                 const uint* __restrict__ ell,
                                                 const float* __restrict__ dinv,
                                                 const ushort* __restrict__ h,
                                                 const float* __restrict__ b,
                                                 ushort* __restrict__ outp) {
    int node = blockIdx.x * 4 + (threadIdx.x >> 6);
    int lane = threadIdx.x & 63;
    if (node >= NN) return;
    int n = cnt[node];
    float di = dinv[node];
    uint rec = ell[(size_t)node * CAP + lane];
    int ce = (int)(rec & 0xffffu);
    float we = (float)(rec >> 16) * EWS;
    uint hp = *(const uint*)&h[(size_t)node * 128 + lane * 2];
    float ax = __uint_as_float(hp << 16);
    float ay = __uint_as_float(hp & 0xffff0000u);
    int j = 0;
    for (; j + 3 < n; j += 4) {
        int s0 = __shfl(ce, j + 0), s1 = __shfl(ce, j + 1);
        int s2 = __shfl(ce, j + 2), s3 = __shfl(ce, j + 3);
        float w0 = __shfl(we, j + 0), w1 = __shfl(we, j + 1);
        float w2 = __shfl(we, j + 2), w3 = __shfl(we, j + 3);
        uint p0 = *(const uint*)&h[(size_t)s0 * 128 + lane * 2];
        uint p1 = *(const uint*)&h[(size_t)s1 * 128 + lane * 2];
        uint p2 = *(const uint*)&h[(size_t)s2 * 128 + lane * 2];
        uint p3 = *(const uint*)&h[(size_t)s3 * 128 + lane * 2];
        ax += w0 * __uint_as_float(p0 << 16) + w1 * __uint_as_float(p1 << 16)
            + w2 * __uint_as_float(p2 << 16) + w3 * __uint_as_float(p3 << 16);
        ay += w0 * __uint_as_float(p0 & 0xffff0000u) + w1 * __uint_as_float(p1 & 0xffff0000u)
            + w2 * __uint_as_float(p2 & 0xffff0000u) + w3 * __uint_as_float(p3 & 0xffff0000u);
    }
    for (; j < n; j++) {
        int s0 = __shfl(ce, j);
        float w0 = __shfl(we, j);
        uint p0 = *(const uint*)&h[(size_t)s0 * 128 + lane * 2];
        ax += w0 * __uint_as_float(p0 << 16);
        ay += w0 * __uint_as_float(p0 & 0xffff0000u);
    }
    ax = fmaxf(di * ax + b[lane * 2 + 0], 0.0f);
    ay = fmaxf(di * ay + b[lane * 2 + 1], 0.0f);
    uint o = ((uint)f2bf(ay) << 16) | (uint)f2bf(ax);
    *(uint*)&outp[(size_t)node * 128 + lane * 2] = o;
}

// ---- gather layer 2 fused with W3 matvec:
//      vec = relu(dinv_d*(sum ew*h'[s] + h'[d]) + b2)  (held in regs, fp32)
//      z[node] = dinv_d * (vec @ W3)   (10-wide, shfl-reduced) ----
__global__ __launch_bounds__(256) void k_gather2z(const int* __restrict__ cnt,
                                                  const uint* __restrict__ ell,
                                                  const float* __restrict__ dinv,
                                                  const ushort* __restrict__ h,
                                                  const float* __restrict__ b,
                                                  const float* __restrict__ W3,
                                                  float* __restrict__ z) {
    int lane = threadIdx.x & 63;
    int gwave = blockIdx.x * 4 + (threadIdx.x >> 6);
    // per-lane W3 rows 2*lane, 2*lane+1 (20 fp32 in registers), bias
    float w3a[10], w3b[10];
    const float* wrow = &W3[lane * 20];
#pragma unroll
    for (int f = 0; f < 10; f++) { w3a[f] = wrow[f]; w3b[f] = wrow[10 + f]; }
    float bx = b[lane * 2 + 0], by = b[lane * 2 + 1];

    for (int node = gwave; node < NN; node += 12500) {
        int n = cnt[node];
        float di = dinv[node];
        uint rec = ell[(size_t)node * CAP + lane];
        int ce = (int)(rec & 0xffffu);
        float we = (float)(rec >> 16) * EWS;
        uint hp = *(const uint*)&h[(size_t)node * 128 + lane * 2];
        float ax = __uint_as_float(hp << 16);
        float ay = __uint_as_float(hp & 0xffff0000u);
        int j = 0;
        for (; j + 3 < n; j += 4) {
            int s0 = __shfl(ce, j + 0), s1 = __shfl(ce, j + 1);
            int s2 = __shfl(ce, j + 2), s3 = __shfl(ce, j + 3);
            float w0 = __shfl(we, j + 0), w1 = __shfl(we, j + 1);
            float w2 = __shfl(we, j + 2), w3 = __shfl(we, j + 3);
            uint p0 = *(const uint*)&h[(size_t)s0 * 128 + lane * 2];
            uint p1 = *(const uint*)&h[(size_t)s1 * 128 + lane * 2];
            uint p2 = *(const uint*)&h[(size_t)s2 * 128 + lane * 2];
            uint p3 = *(const uint*)&h[(size_t)s3 * 128 + lane * 2];
            ax += w0 * __uint_as_float(p0 << 16) + w1 * __uint_as_float(p1 << 16)
                + w2 * __uint_as_float(p2 << 16) + w3 * __uint_as_float(p3 << 16);
            ay += w0 * __uint_as_float(p0 & 0xffff0000u) + w1 * __uint_as_float(p1 & 0xffff0000u)
                + w2 * __uint_as_float(p2 & 0xffff0000u) + w3 * __uint_as_float(p3 & 0xffff0000u);
        }
        for (; j < n; j++) {
            int s0 = __shfl(ce, j);
            float w0 = __shfl(we, j);
            uint p0 = *(const uint*)&h[(size_t)s0 * 128 + lane * 2];
            ax += w0 * __uint_as_float(p0 << 16);
            ay += w0 * __uint_as_float(p0 & 0xffff0000u);
        }
        ax = fmaxf(di * ax + bx, 0.0f);
        ay = fmaxf(di * ay + by, 0.0f);
        // fused z = di * (vec @ W3)
        float p[10];
#pragma unroll
        for (int f = 0; f < 10; f++) p[f] = ax * w3a[f] + ay * w3b[f];
#pragma unroll
        for (int off = 32; off; off >>= 1) {
#pragma unroll
            for (int f = 0; f < 10; f++) p[f] += __shfl_down(p[f], off);
        }
        if (lane == 0) {
            float* zp = &z[(size_t)node * 10];
#pragma unroll
            for (int f = 0; f < 10; f++) zp[f] = di * p[f];
        }
    }
}

// ---- pool: wave per node over ELL; LDS bins -> global atomic flush;
//      last block computes log_softmax in-place ----
__global__ __launch_bounds__(256) void k_pool(const int* __restrict__ cnt,
                                              const uint* __restrict__ ell,
                                              const float* __restrict__ dinv,
                                              const float* __restrict__ z,
                                              const int* __restrict__ batch,
                                              float* __restrict__ sums,
                                              int* __restrict__ done,
                                              const float* __restrict__ b3,
                                              float* __restrict__ out) {
    __shared__ float ls[NG * CO + NG];
    __shared__ int last;
    int tid = threadIdx.x;
    for (int i = tid; i < NG * CO + NG; i += 256) ls[i] = 0.0f;
    __syncthreads();
    int lane = tid & 63;
    int gwave = blockIdx.x * 4 + (tid >> 6);
    for (int node = gwave; node < NN; node += NPB * 4) {
        int n = cnt[node];
        float w = 0.0f; int s = 0;
        if (lane < n) {
            uint rec = ell[(size_t)node * CAP + lane];
            s = (int)(rec & 0xffffu);
            w = (float)(rec >> 16) * EWS;
        } else if (lane == n) {
            s = node;
            w = 1.0f;
        }
        const float* zp = &z[(size_t)s * 10];
        float v[10];
#pragma unroll
        for (int f = 0; f < 10; f++) v[f] = w * zp[f];
#pragma unroll
        for (int off = 32; off; off >>= 1) {
#pragma unroll
            for (int f = 0; f < 10; f++) v[f] += __shfl_down(v[f], off);
        }
        if (lane == 0) {
            int g = batch[node];
            float di = dinv[node];
            float* lp = &ls[g * 10];
#pragma unroll
            for (int f = 0; f < 10; f++) atomicAdd(&lp[f], di * v[f]);
            atomicAdd(&ls[NG * CO + g], 1.0f);
        }
    }
    __syncthreads();
    for (int i = tid; i < NG * CO + NG; i += 256) {
        float v = ls[i];
        if (v != 0.0f) atomicAdd(&sums[i], v);
    }
    __threadfence();
    if (tid == 0) last = (atomicAdd(done, 1) == NPB - 1);
    __syncthreads();
    if (last && tid < NG) {
        int g = tid;
        float cc = __hip_atomic_load(&sums[NG * CO + g], __ATOMIC_RELAXED,
                                     __HIP_MEMORY_SCOPE_AGENT);
        cc = fmaxf(cc, 1.0f);
        float p[10], m = -1e30f;
#pragma unroll
        for (int f = 0; f < 10; f++) {
            float sv = __hip_atomic_load(&sums[g * 10 + f], __ATOMIC_RELAXED,
                                         __HIP_MEMORY_SCOPE_AGENT);
            p[f] = sv / cc + b3[f];
            m = fmaxf(m, p[f]);
        }
        float ssum = 0.0f;
#pragma unroll
        for (int f = 0; f < 10; f++) ssum += __expf(p[f] - m);
        float lse = m + __logf(ssum);
#pragma unroll
        for (int f = 0; f < 10; f++) out[g * 10 + f] = p[f] - lse;
    }
}

extern "C" void kernel_launch(void* const* d_in, const int* in_sizes, int n_in,
                              void* d_out, int out_size, void* d_ws, size_t ws_size,
                              hipStream_t stream) {
    const float* x     = (const float*)d_in[0];
    const int*   ei    = (const int*)d_in[1];     // [2, E]
    const float* ea    = (const float*)d_in[2];
    const int*   batch = (const int*)d_in[3];
    const float* W1    = (const float*)d_in[4];
    const float* b1    = (const float*)d_in[5];
    const float* W2    = (const float*)d_in[6];
    const float* b2    = (const float*)d_in[7];
    const float* W3    = (const float*)d_in[8];
    const float* b3    = (const float*)d_in[9];
    float* out = (float*)d_out;
    float* ws  = (float*)d_ws;

    const int* esrc = ei;
    const int* edst = ei + NE;

    // workspace layout (float offsets; 16B aligned)
    ushort* hb   = (ushort*)ws;                 // N*128 bf16 = 3,200,000 floats
    ushort* gb   = (ushort*)(ws + 3200000);     // N*128 bf16 = 3,200,000 floats
    float*  z    = ws + 6400000;                // 500,000
    float*  dinv = ws + 6900000;                // 50,000
    int*    cnt  = (int*)(ws + 6950000);        // 50,000 ints
    uint*   ell  = (uint*)(ws + 7000000);       // NN*CAP u32 = 3,200,000
    ushort* wt1  = (ushort*)(ws + 10200000);    // 16384 ushorts
    ushort* wt2  = (ushort*)(ws + 10210000);    // 16384 ushorts
    float*  sums = ws + 10220000;               // 1408 floats
    int*    done = (int*)(ws + 10221500);       // 1 int

    // 1. prep (wt1, wt2, cnt=0, sums=0, done=0)
    k_prep<<<330, 256, 0, stream>>>(W1, W2, wt1, wt2, cnt, sums, done);
    // 2. ELL build
    k_ell<<<(NE + 255) / 256, 256, 0, stream>>>(esrc, edst, ea, cnt, ell);
    // 3. gemm1 + deg: dinv + h' = dinv*(X@W1)
    k_gemm1<<<GEMB, 256, 0, stream>>>(x, wt1, cnt, ell, dinv, hb);
    // 4. gather layer 1 -> gb
    k_gather1<<<(NN + 3) / 4, 256, 0, stream>>>(cnt, ell, dinv, hb, b1, gb);
    // 5. gemm2: h' = dinv*(gb@W2)
    k_gemm2<<<GEMB, 256, 0, stream>>>(gb, wt2, dinv, hb);
    // 6. gather layer 2 + W3 matvec -> z
    k_gather2z<<<3125, 256, 0, stream>>>(cnt, ell, dinv, hb, b2, W3, z);
    // 7. pool + log_softmax (last-block finisher)
    k_pool<<<NPB, 256, 0, stream>>>(cnt, ell, dinv, z, batch, sums, done, b3, out);
}

// Round 14
// 324.985 us; speedup vs baseline: 1.3308x; 1.3308x over previous
//
#include <hip/hip_runtime.h>

#define NN 50000
#define NE 800000
#define NG 128
#define DIM 128
#define CO 10
#define CAP 64     // ELL row capacity; Poisson(16) tail beyond 64 is ~1e-20
#define NPB 2048   // pool stage-1 blocks
#define GEMB 782   // (NN+63)/64 gemm tile-blocks

typedef unsigned short ushort;
typedef unsigned int uint;
typedef __attribute__((ext_vector_type(8))) short short8;   // 8 bf16
typedef __attribute__((ext_vector_type(4))) float floatx4;

static __device__ __forceinline__ ushort f2bf(float f) {
    uint u = __float_as_uint(f);
    uint r = (u + 0x7FFF + ((u >> 16) & 1)) >> 16;   // RNE
    return (ushort)r;
}
#define EWS (1.0f / 65535.0f)

// ---- prep: wt = bf16(W^T) x2, cnt = 0 (one launch) ----
__global__ void k_prep(const float* __restrict__ W1, const float* __restrict__ W2,
                       ushort* __restrict__ wt1, ushort* __restrict__ wt2,
                       int* __restrict__ cnt) {
    int i = blockIdx.x * 256 + threadIdx.x;
    if (i < 16384) {
        wt1[(i & 127) * 128 + (i >> 7)] = f2bf(W1[i]);
    } else if (i < 32768) {
        int j = i - 16384;
        wt2[(j & 127) * 128 + (j >> 7)] = f2bf(W2[j]);
    } else if (i < 32768 + NN) {
        cnt[i - 32768] = 0;
    }
}

// ---- ELL build: 4B record (ew_u16 << 16 | src_u16) ----
__global__ void k_ell(const int* __restrict__ src, const int* __restrict__ dst,
                      const float* __restrict__ ew, int* __restrict__ cnt,
                      uint* __restrict__ ell) {
    int e = blockIdx.x * blockDim.x + threadIdx.x;
    if (e >= NE) return;
    int d = dst[e], s = src[e];
    int slot = atomicAdd(&cnt[d], 1);
    if (slot < CAP) {
        uint w16 = (uint)__float2uint_rn(ew[e] * 65535.0f);
        ell[(size_t)d * CAP + slot] = (w16 << 16) | (uint)s;
    }
}

// ---- one wave-tile of the MFMA GEMM (16 rows x 128 cols) ----
static __device__ __forceinline__ void gemm_tile(const void* Ain, int abf,
                                                 const ushort* Wt,
                                                 const float* dglob, const float* dlds,
                                                 ushort* C, int M, int r0, int lane) {
    int quad = lane >> 4;
    int mcol = lane & 15;
    int arow = r0 + mcol;
    if (arow >= M) arow = M - 1;
    floatx4 acc[8];
#pragma unroll
    for (int t = 0; t < 8; t++) acc[t] = (floatx4){0.0f, 0.0f, 0.0f, 0.0f};
    const ushort* Ab = (const ushort*)Ain;
    const float*  Af = (const float*)Ain;
#pragma unroll
    for (int kk = 0; kk < 4; kk++) {
        int koff = kk * 32 + quad * 8;
        short8 a;
        if (abf) {
            a = *(const short8*)&Ab[(size_t)arow * 128 + koff];
        } else {
            const float* ap = &Af[(size_t)arow * 128 + koff];
            float4 x0 = *(const float4*)ap;
            float4 x1 = *(const float4*)(ap + 4);
            union { short8 v; ushort u[8]; } ua;
            ua.u[0] = f2bf(x0.x); ua.u[1] = f2bf(x0.y); ua.u[2] = f2bf(x0.z); ua.u[3] = f2bf(x0.w);
            ua.u[4] = f2bf(x1.x); ua.u[5] = f2bf(x1.y); ua.u[6] = f2bf(x1.z); ua.u[7] = f2bf(x1.w);
            a = ua.v;
        }
#pragma unroll
        for (int t = 0; t < 8; t++) {
            short8 b = *(const short8*)&Wt[(size_t)(t * 16 + mcol) * 128 + koff];
            acc[t] = __builtin_amdgcn_mfma_f32_16x16x32_bf16(a, b, acc[t], 0, 0, 0);
        }
    }
#pragma unroll
    for (int reg = 0; reg < 4; reg++) {
        int row = r0 + quad * 4 + reg;
        if (row < M) {
            float di = dglob ? dglob[row] : (dlds ? dlds[quad * 4 + reg] : 1.0f);
            ushort* cp = &C[(size_t)row * 128];
#pragma unroll
            for (int t = 0; t < 8; t++) cp[t * 16 + mcol] = f2bf(di * acc[t][reg]);
        }
    }
}

// ---- gemm1 + deg: wave computes dinv for its 16 rows, then h' = bf16(dinv⊙(X@W1)) ----
__global__ __launch_bounds__(256) void k_gemm1(const float* __restrict__ x,
                                               const ushort* __restrict__ wt1,
                                               const int* __restrict__ cnt,
                                               const uint* __restrict__ ell,
                                               float* __restrict__ dinv,
                                               ushort* __restrict__ hb) {
    __shared__ float sdinv[4][16];
    int wv = threadIdx.x >> 6;
    int lane = threadIdx.x & 63;
    int r0 = blockIdx.x * 64 + wv * 16;
#pragma unroll 4
    for (int r = 0; r < 16; r++) {
        int row = r0 + r;
        if (row < NN) {
            int n = cnt[row];
            float w = (lane < n) ? (float)(ell[(size_t)row * CAP + lane] >> 16) * EWS : 0.0f;
#pragma unroll
            for (int off = 32; off; off >>= 1) w += __shfl_down(w, off);
            if (lane == 0) {
                float dv = rsqrtf(1.0f + w);
                dinv[row] = dv;
                sdinv[wv][r] = dv;
            }
        }
    }
    gemm_tile(x, 0, wt1, nullptr, &sdinv[wv][0], hb, NN, r0, lane);
}

// ---- gemm2: C = bf16(dinv ⊙ (A(bf16) @ W2)) ----
__global__ __launch_bounds__(256) void k_gemm2(const ushort* __restrict__ A,
                                               const ushort* __restrict__ wt2,
                                               const float* __restrict__ dinv,
                                               ushort* __restrict__ C) {
    int wv = threadIdx.x >> 6;
    int lane = threadIdx.x & 63;
    gemm_tile(A, 1, wt2, dinv, nullptr, C, NN, blockIdx.x * 64 + wv * 16, lane);
}

// ---- gather layer 1: gb = bf16(relu(dinv_d*(sum ew*h'[s] + h'[d]) + b1)) ----
__global__ __launch_bounds__(256) void k_gather1(const int* __restrict__ cnt,
                                                 const uint* __restrict__ ell,
                                                 const float* __restrict__ dinv,
                                                 const ushort* __restrict__ h,
                                                 const float* __restrict__ b,
                                                 ushort* __restrict__ outp) {
    int node = blockIdx.x * 4 + (threadIdx.x >> 6);
    int lane = threadIdx.x & 63;
    if (node >= NN) return;
    int n = cnt[node];
    float di = dinv[node];
    uint rec = ell[(size_t)node * CAP + lane];
    int ce = (int)(rec & 0xffffu);
    float we = (float)(rec >> 16) * EWS;
    uint hp = *(const uint*)&h[(size_t)node * 128 + lane * 2];
    float ax = __uint_as_float(hp << 16);
    float ay = __uint_as_float(hp & 0xffff0000u);
    int j = 0;
    for (; j + 3 < n; j += 4) {
        int s0 = __shfl(ce, j + 0), s1 = __shfl(ce, j + 1);
        int s2 = __shfl(ce, j + 2), s3 = __shfl(ce, j + 3);
        float w0 = __shfl(we, j + 0), w1 = __shfl(we, j + 1);
        float w2 = __shfl(we, j + 2), w3 = __shfl(we, j + 3);
        uint p0 = *(const uint*)&h[(size_t)s0 * 128 + lane * 2];
        uint p1 = *(const uint*)&h[(size_t)s1 * 128 + lane * 2];
        uint p2 = *(const uint*)&h[(size_t)s2 * 128 + lane * 2];
        uint p3 = *(const uint*)&h[(size_t)s3 * 128 + lane * 2];
        ax += w0 * __uint_as_float(p0 << 16) + w1 * __uint_as_float(p1 << 16)
            + w2 * __uint_as_float(p2 << 16) + w3 * __uint_as_float(p3 << 16);
        ay += w0 * __uint_as_float(p0 & 0xffff0000u) + w1 * __uint_as_float(p1 & 0xffff0000u)
            + w2 * __uint_as_float(p2 & 0xffff0000u) + w3 * __uint_as_float(p3 & 0xffff0000u);
    }
    for (; j < n; j++) {
        int s0 = __shfl(ce, j);
        float w0 = __shfl(we, j);
        uint p0 = *(const uint*)&h[(size_t)s0 * 128 + lane * 2];
        ax += w0 * __uint_as_float(p0 << 16);
        ay += w0 * __uint_as_float(p0 & 0xffff0000u);
    }
    ax = fmaxf(di * ax + b[lane * 2 + 0], 0.0f);
    ay = fmaxf(di * ay + b[lane * 2 + 1], 0.0f);
    uint o = ((uint)f2bf(ay) << 16) | (uint)f2bf(ax);
    *(uint*)&outp[(size_t)node * 128 + lane * 2] = o;
}

// ---- gather layer 2 fused with W3 matvec: z[node] = dinv_d*(relu(...)@W3) ----
__global__ __launch_bounds__(256) void k_gather2z(const int* __restrict__ cnt,
                                                  const uint* __restrict__ ell,
                                                  const float* __restrict__ dinv,
                                                  const ushort* __restrict__ h,
                                                  const float* __restrict__ b,
                                                  const float* __restrict__ W3,
                                                  float* __restrict__ z) {
    int lane = threadIdx.x & 63;
    int gwave = blockIdx.x * 4 + (threadIdx.x >> 6);
    float w3a[10], w3b[10];
    const float* wrow = &W3[lane * 20];
#pragma unroll
    for (int f = 0; f < 10; f++) { w3a[f] = wrow[f]; w3b[f] = wrow[10 + f]; }
    float bx = b[lane * 2 + 0], by = b[lane * 2 + 1];

    for (int node = gwave; node < NN; node += 12500) {
        int n = cnt[node];
        float di = dinv[node];
        uint rec = ell[(size_t)node * CAP + lane];
        int ce = (int)(rec & 0xffffu);
        float we = (float)(rec >> 16) * EWS;
        uint hp = *(const uint*)&h[(size_t)node * 128 + lane * 2];
        float ax = __uint_as_float(hp << 16);
        float ay = __uint_as_float(hp & 0xffff0000u);
        int j = 0;
        for (; j + 3 < n; j += 4) {
            int s0 = __shfl(ce, j + 0), s1 = __shfl(ce, j + 1);
            int s2 = __shfl(ce, j + 2), s3 = __shfl(ce, j + 3);
            float w0 = __shfl(we, j + 0), w1 = __shfl(we, j + 1);
            float w2 = __shfl(we, j + 2), w3 = __shfl(we, j + 3);
            uint p0 = *(const uint*)&h[(size_t)s0 * 128 + lane * 2];
            uint p1 = *(const uint*)&h[(size_t)s1 * 128 + lane * 2];
            uint p2 = *(const uint*)&h[(size_t)s2 * 128 + lane * 2];
            uint p3 = *(const uint*)&h[(size_t)s3 * 128 + lane * 2];
            ax += w0 * __uint_as_float(p0 << 16) + w1 * __uint_as_float(p1 << 16)
                + w2 * __uint_as_float(p2 << 16) + w3 * __uint_as_float(p3 << 16);
            ay += w0 * __uint_as_float(p0 & 0xffff0000u) + w1 * __uint_as_float(p1 & 0xffff0000u)
                + w2 * __uint_as_float(p2 & 0xffff0000u) + w3 * __uint_as_float(p3 & 0xffff0000u);
        }
        for (; j < n; j++) {
            int s0 = __shfl(ce, j);
            float w0 = __shfl(we, j);
            uint p0 = *(const uint*)&h[(size_t)s0 * 128 + lane * 2];
            ax += w0 * __uint_as_float(p0 << 16);
            ay += w0 * __uint_as_float(p0 & 0xffff0000u);
        }
        ax = fmaxf(di * ax + bx, 0.0f);
        ay = fmaxf(di * ay + by, 0.0f);
        float p[10];
#pragma unroll
        for (int f = 0; f < 10; f++) p[f] = ax * w3a[f] + ay * w3b[f];
#pragma unroll
        for (int off = 32; off; off >>= 1) {
#pragma unroll
            for (int f = 0; f < 10; f++) p[f] += __shfl_down(p[f], off);
        }
        if (lane == 0) {
            float* zp = &z[(size_t)node * 10];
#pragma unroll
            for (int f = 0; f < 10; f++) zp[f] = di * p[f];
        }
    }
}

// ---- pool stage 1: wave per node; LDS bins -> PLAIN partial stores ----
__global__ __launch_bounds__(256) void k_pool_node(const int* __restrict__ cnt,
                                                   const uint* __restrict__ ell,
                                                   const float* __restrict__ dinv,
                                                   const float* __restrict__ z,
                                                   const int* __restrict__ batch,
                                                   float* __restrict__ partial) {
    __shared__ float ls[NG * CO + NG];
    for (int i = threadIdx.x; i < NG * CO + NG; i += 256) ls[i] = 0.0f;
    __syncthreads();
    int lane = threadIdx.x & 63;
    int gwave = blockIdx.x * 4 + (threadIdx.x >> 6);
    for (int node = gwave; node < NN; node += NPB * 4) {
        int n = cnt[node];
        float w = 0.0f; int s = 0;
        if (lane < n) {
            uint rec = ell[(size_t)node * CAP + lane];
            s = (int)(rec & 0xffffu);
            w = (float)(rec >> 16) * EWS;
        } else if (lane == n) {
            s = node;
            w = 1.0f;
        }
        const float* zp = &z[(size_t)s * 10];
        float v[10];
#pragma unroll
        for (int f = 0; f < 10; f++) v[f] = w * zp[f];
#pragma unroll
        for (int off = 32; off; off >>= 1) {
#pragma unroll
            for (int f = 0; f < 10; f++) v[f] += __shfl_down(v[f], off);
        }
        if (lane == 0) {
            int g = batch[node];
            float di = dinv[node];
            float* lp = &ls[g * 10];
#pragma unroll
            for (int f = 0; f < 10; f++) atomicAdd(&lp[f], di * v[f]);
            atomicAdd(&ls[NG * CO + g], 1.0f);
        }
    }
    __syncthreads();
    float* pb = &partial[(size_t)blockIdx.x * (NG * CO + NG)];
    for (int i = threadIdx.x; i < NG * CO + NG; i += 256) pb[i] = ls[i];
}

// ---- pool stage 2 + log_softmax: one block (256 thr) per graph ----
__global__ __launch_bounds__(256) void k_pool_final(const float* __restrict__ partial,
                                                    const float* __restrict__ b3,
                                                    float* __restrict__ out) {
    __shared__ float red[4][11];
    int g = blockIdx.x;
    int t = threadIdx.x;
    int lane = t & 63, wv = t >> 6;
    float v[10]; float c = 0.0f;
#pragma unroll
    for (int f = 0; f < 10; f++) v[f] = 0.0f;
    for (int b = t; b < NPB; b += 256) {
        const float* pb = &partial[(size_t)b * (NG * CO + NG)];
#pragma unroll
        for (int f = 0; f < 10; f++) v[f] += pb[g * 10 + f];
        c += pb[NG * CO + g];
    }
#pragma unroll
    for (int off = 32; off; off >>= 1) {
#pragma unroll
        for (int f = 0; f < 10; f++) v[f] += __shfl_down(v[f], off);
        c += __shfl_down(c, off);
    }
    if (lane == 0) {
#pragma unroll
        for (int f = 0; f < 10; f++) red[wv][f] = v[f];
        red[wv][10] = c;
    }
    __syncthreads();
    if (t == 0) {
        float p[10], m = -1e30f;
        float cc = red[0][10] + red[1][10] + red[2][10] + red[3][10];
        cc = fmaxf(cc, 1.0f);
#pragma unroll
        for (int f = 0; f < 10; f++) {
            p[f] = (red[0][f] + red[1][f] + red[2][f] + red[3][f]) / cc + b3[f];
            m = fmaxf(m, p[f]);
        }
        float ssum = 0.0f;
#pragma unroll
        for (int f = 0; f < 10; f++) ssum += __expf(p[f] - m);
        float lse = m + __logf(ssum);
#pragma unroll
        for (int f = 0; f < 10; f++) out[g * 10 + f] = p[f] - lse;
    }
}

extern "C" void kernel_launch(void* const* d_in, const int* in_sizes, int n_in,
                              void* d_out, int out_size, void* d_ws, size_t ws_size,
                              hipStream_t stream) {
    const float* x     = (const float*)d_in[0];
    const int*   ei    = (const int*)d_in[1];     // [2, E]
    const float* ea    = (const float*)d_in[2];
    const int*   batch = (const int*)d_in[3];
    const float* W1    = (const float*)d_in[4];
    const float* b1    = (const float*)d_in[5];
    const float* W2    = (const float*)d_in[6];
    const float* b2    = (const float*)d_in[7];
    const float* W3    = (const float*)d_in[8];
    const float* b3    = (const float*)d_in[9];
    float* out = (float*)d_out;
    float* ws  = (float*)d_ws;

    const int* esrc = ei;
    const int* edst = ei + NE;

    // workspace layout (float offsets; 16B aligned)
    ushort* hb      = (ushort*)ws;                 // N*128 bf16 = 3,200,000 floats
    ushort* gb      = (ushort*)(ws + 3200000);     // N*128 bf16 = 3,200,000 floats
    float*  z       = ws + 6400000;                // 500,000
    float*  dinv    = ws + 6900000;                // 50,000
    int*    cnt     = (int*)(ws + 6950000);        // 50,000 ints
    uint*   ell     = (uint*)(ws + 7000000);       // NN*CAP u32 = 3,200,000
    ushort* wt1     = (ushort*)(ws + 10200000);    // 16384 ushorts
    ushort* wt2     = (ushort*)(ws + 10210000);    // 16384 ushorts
    float*  partial = (float*)hb;                  // NPB*1408 = 2,883,584 floats, overlays hb
                                                   // (hb dead after gather2z)

    // 1. prep (wt1, wt2, cnt=0)
    k_prep<<<330, 256, 0, stream>>>(W1, W2, wt1, wt2, cnt);
    // 2. ELL build
    k_ell<<<(NE + 255) / 256, 256, 0, stream>>>(esrc, edst, ea, cnt, ell);
    // 3. gemm1 + deg: dinv + h' = dinv*(X@W1)
    k_gemm1<<<GEMB, 256, 0, stream>>>(x, wt1, cnt, ell, dinv, hb);
    // 4. gather layer 1 -> gb
    k_gather1<<<(NN + 3) / 4, 256, 0, stream>>>(cnt, ell, dinv, hb, b1, gb);
    // 5. gemm2: h' = dinv*(gb@W2)
    k_gemm2<<<GEMB, 256, 0, stream>>>(gb, wt2, dinv, hb);
    // 6. gather layer 2 + W3 matvec -> z
    k_gather2z<<<3125, 256, 0, stream>>>(cnt, ell, dinv, hb, b2, W3, z);
    // 7. pool stage 1 (plain partial stores)
    k_pool_node<<<NPB, 256, 0, stream>>>(cnt, ell, dinv, z, batch, partial);
    // 8. pool stage 2 + log_softmax
    k_pool_final<<<NG, 256, 0, stream>>>(partial, b3, out);
}